// Round 6
// baseline (334.698 us; speedup 1.0000x reference)
//
#include <hip/hip_runtime.h>
#include <math.h>
#include <stdint.h>

static __device__ __forceinline__ float lrelu(float x) { return x >= 0.f ? x : 0.2f * x; }

// round-to-nearest-even fp32 -> bf16 bits
static __device__ __forceinline__ uint32_t f2bf(float f) {
    uint32_t u = __float_as_uint(f);
    return (u + 0x7FFFu + ((u >> 16) & 1u)) >> 16;
}

// ---------------- GEMM + alpha body (device function) ----------------
// h[r,128] = x[r,128] @ W[128,128]; writes bf16-packed h, and fused
// as_[r,h] = h.a_src[h], ad_[r,h] = h.a_dst[h] from fp32 registers.
// 128-row tile, BK=32, 256 threads as 16 rowgrp x 16 colgrp, 8x8/thread.
static __device__ void gemm_alpha_body(const float* __restrict__ x,
                                       const float* __restrict__ W,
                                       const float* __restrict__ a_src,
                                       const float* __restrict__ a_dst,
                                       uint32_t* __restrict__ hbf,
                                       float* __restrict__ as_,
                                       float* __restrict__ ad_,
                                       int nrows, int blk,
                                       float* xs, float* ws) {
    const int t = threadIdx.x;
    const int row0 = blk * 128;
    const int rg = t >> 4;           // 0..15
    const int cg = t & 15;           // 0..15
    const int r0 = rg * 8;
    const int c0 = cg * 8;

    float acc[8][8];
    #pragma unroll
    for (int j = 0; j < 8; ++j)
        #pragma unroll
        for (int c = 0; c < 8; ++c) acc[j][c] = 0.f;

    const float4* x4 = (const float4*)x;
    const float4* W4 = (const float4*)W;
    float4* xs4 = (float4*)xs;
    float4* ws4 = (float4*)ws;

    for (int kc = 0; kc < 4; ++kc) {
        #pragma unroll
        for (int i = 0; i < 4; ++i) {       // stage x chunk [128 rows][32 k]
            int idx = t + i * 256;           // 0..1023
            int r = idx >> 3, q = idx & 7;
            float4 v = make_float4(0.f, 0.f, 0.f, 0.f);
            if (row0 + r < nrows) v = x4[(size_t)(row0 + r) * 32 + kc * 8 + q];
            xs4[idx] = v;
        }
        #pragma unroll
        for (int i = 0; i < 4; ++i) {       // stage W chunk [32 k][128 cols]
            int idx = t + i * 256;
            ws4[idx] = W4[kc * 1024 + idx];
        }
        __syncthreads();

        #pragma unroll 2
        for (int kk = 0; kk < 32; kk += 4) {
            float4 xv[8];
            #pragma unroll
            for (int j = 0; j < 8; ++j)
                xv[j] = xs4[(r0 + j) * 8 + (kk >> 2)];
            #pragma unroll
            for (int k2 = 0; k2 < 4; ++k2) {
                int k = kk + k2;
                float4 wv0 = ws4[k * 32 + cg * 2];
                float4 wv1 = ws4[k * 32 + cg * 2 + 1];
                #pragma unroll
                for (int j = 0; j < 8; ++j) {
                    float xk = (k2 == 0) ? xv[j].x : (k2 == 1) ? xv[j].y
                             : (k2 == 2) ? xv[j].z : xv[j].w;
                    acc[j][0] = fmaf(xk, wv0.x, acc[j][0]);
                    acc[j][1] = fmaf(xk, wv0.y, acc[j][1]);
                    acc[j][2] = fmaf(xk, wv0.z, acc[j][2]);
                    acc[j][3] = fmaf(xk, wv0.w, acc[j][3]);
                    acc[j][4] = fmaf(xk, wv1.x, acc[j][4]);
                    acc[j][5] = fmaf(xk, wv1.y, acc[j][5]);
                    acc[j][6] = fmaf(xk, wv1.z, acc[j][6]);
                    acc[j][7] = fmaf(xk, wv1.w, acc[j][7]);
                }
            }
        }
        __syncthreads();
    }

    // epilogue: bf16 h + fused alpha dots (head hd = cg>>2).
    const int hd = cg >> 2;
    float asv[8], adv[8];
    #pragma unroll
    for (int cc = 0; cc < 8; ++cc) {
        asv[cc] = a_src[c0 + cc];
        adv[cc] = a_dst[c0 + cc];
    }
    #pragma unroll
    for (int j = 0; j < 8; ++j) {
        int r = row0 + r0 + j;
        float ps = 0.f, pd = 0.f;
        #pragma unroll
        for (int cc = 0; cc < 8; ++cc) {
            ps = fmaf(acc[j][cc], asv[cc], ps);
            pd = fmaf(acc[j][cc], adv[cc], pd);
        }
        ps += __shfl_xor(ps, 1); ps += __shfl_xor(ps, 2);
        pd += __shfl_xor(pd, 1); pd += __shfl_xor(pd, 2);
        if (r < nrows) {
            uint4 pk;
            pk.x = f2bf(acc[j][0]) | (f2bf(acc[j][1]) << 16);
            pk.y = f2bf(acc[j][2]) | (f2bf(acc[j][3]) << 16);
            pk.z = f2bf(acc[j][4]) | (f2bf(acc[j][5]) << 16);
            pk.w = f2bf(acc[j][6]) | (f2bf(acc[j][7]) << 16);
            *(uint4*)&hbf[(size_t)r * 64 + cg * 4] = pk;
            if ((cg & 3) == 0) {
                as_[r * 4 + hd] = ps;
                ad_[r * 4 + hd] = pd;
            }
        }
    }
}

// Fused: blocks [0,gb) run gemm_alpha for layer 1; blocks [gb, gb+eb) run
// count_rank (independent work; co-scheduling hides atomic-return latency
// under FMA issue — a single in-order stream would serialize them).
__global__ __launch_bounds__(256) void gemm_count(const float* __restrict__ x,
                                                  const float* __restrict__ W,
                                                  const float* __restrict__ a_src,
                                                  const float* __restrict__ a_dst,
                                                  uint32_t* __restrict__ hbf,
                                                  float* __restrict__ as_,
                                                  float* __restrict__ ad_,
                                                  int nrows, int gb,
                                                  const int* __restrict__ dst, int E,
                                                  int* __restrict__ deg,
                                                  int* __restrict__ rank) {
    __shared__ float xs[128 * 32];
    __shared__ float ws[32 * 128];
    if ((int)blockIdx.x < gb) {
        gemm_alpha_body(x, W, a_src, a_dst, hbf, as_, ad_, nrows, blockIdx.x, xs, ws);
    } else {
        int i = (blockIdx.x - gb) * 256 + threadIdx.x;
        if (i < E) rank[i] = atomicAdd(&deg[dst[i]], 1);
    }
}

// Standalone gemm+alpha for layer 2.
__global__ __launch_bounds__(256) void gemm_alpha(const float* __restrict__ x,
                                                  const float* __restrict__ W,
                                                  const float* __restrict__ a_src,
                                                  const float* __restrict__ a_dst,
                                                  uint32_t* __restrict__ hbf,
                                                  float* __restrict__ as_,
                                                  float* __restrict__ ad_,
                                                  int nrows) {
    __shared__ float xs[128 * 32];
    __shared__ float ws[32 * 128];
    gemm_alpha_body(x, W, a_src, a_dst, hbf, as_, ad_, nrows, blockIdx.x, xs, ws);
}

// ---------------- CSR build (padded to multiple of 8) ----------------
__global__ __launch_bounds__(256) void scan1(const int* __restrict__ deg, int N, int ntot,
                                             int* __restrict__ rowptr, int* __restrict__ csum) {
    __shared__ int s[256];
    int t = threadIdx.x;
    int i = blockIdx.x * 256 + t;
    int v = (i < N) ? ((deg[i] + 7) & ~7) : 0;   // PADDED degree
    s[t] = v;
    __syncthreads();
    #pragma unroll
    for (int off = 1; off < 256; off <<= 1) {
        int add = (t >= off) ? s[t - off] : 0;
        __syncthreads();
        s[t] += add;
        __syncthreads();
    }
    if (i < ntot) rowptr[i] = s[t] - v;   // exclusive within chunk
    if (t == 255) csum[blockIdx.x] = s[255];
}

__global__ __launch_bounds__(256) void scan2(const int* __restrict__ csum,
                                             int* __restrict__ coff, int nch) {
    __shared__ int s[256];
    int t = threadIdx.x;
    int v = (t < nch) ? csum[t] : 0;
    s[t] = v;
    __syncthreads();
    #pragma unroll
    for (int off = 1; off < 256; off <<= 1) {
        int add = (t >= off) ? s[t - off] : 0;
        __syncthreads();
        s[t] += add;
        __syncthreads();
    }
    coff[t] = s[t] - v;
}

__global__ __launch_bounds__(256) void scan3(int* __restrict__ rowptr,
                                             const int* __restrict__ coff, int ntot) {
    int i = blockIdx.x * 256 + threadIdx.x;
    if (i < ntot) rowptr[i] += coff[blockIdx.x];
}

// Fill pad slots with sentinel node N (weight exactly 0 via as_[N]=-1e30);
// also writes the sentinel's as_ entries once.
__global__ __launch_bounds__(256) void pad_fill(const int* __restrict__ deg,
                                                const int* __restrict__ rowptr,
                                                int* __restrict__ colidx,
                                                float* __restrict__ as_, int N) {
    int i = blockIdx.x * 256 + threadIdx.x;
    if (i == 0) {
        as_[N * 4 + 0] = -1e30f; as_[N * 4 + 1] = -1e30f;
        as_[N * 4 + 2] = -1e30f; as_[N * 4 + 3] = -1e30f;
    }
    if (i < N) {
        int b = rowptr[i] + deg[i];
        int e = rowptr[i + 1];
        for (int p = b; p < e; ++p) colidx[p] = N;
    }
}

__global__ __launch_bounds__(256) void fill_csr(const int* __restrict__ src,
                                                const int* __restrict__ dst,
                                                const int* __restrict__ rank, int E,
                                                const int* __restrict__ rowptr,
                                                int* __restrict__ colidx) {
    int i = blockIdx.x * 256 + threadIdx.x;
    if (i < E) colidx[rowptr[dst[i]] + rank[i]] = src[i];
}

// ---------------- aggregation: one wave per dst node, bf16 h rows ----------------
// Rows padded to multiple of 8 -> uniform 8-deep MLP batches, no serial tail.
// Weight dedup: lane c=lane&31 computes weight of (edge c>>2, head c&3).
__global__ __launch_bounds__(256) void aggregate(const uint32_t* __restrict__ hb,
                                                 const float* __restrict__ as_,
                                                 const float* __restrict__ ad_,
                                                 const int* __restrict__ rowptr,
                                                 const int* __restrict__ colidx,
                                                 const float* __restrict__ bias,
                                                 float* __restrict__ out, int n, int do_elu) {
    int node = blockIdx.x * 4 + (threadIdx.x >> 6);
    if (node >= n) return;
    int lane = threadIdx.x & 63;
    int hd = lane >> 4;          // head of this lane's 2 output columns
    int k = lane * 2;
    int c = lane & 31;
    int ce = c >> 2;             // edge-in-batch this lane weighs
    int ch = c & 3;              // head this lane weighs
    float adn = ad_[node * 4 + hd];
    float adc = ad_[node * 4 + ch];
    float accx = 0.f, accy = 0.f, denom = 0.f;

    {   // self loop
        float wgt = __expf(lrelu(as_[node * 4 + hd] + adn));
        uint32_t u = hb[(size_t)node * 64 + lane];
        accx = fmaf(wgt, __uint_as_float(u << 16), accx);
        accy = fmaf(wgt, __uint_as_float(u & 0xFFFF0000u), accy);
        denom += wgt;
    }
    const int beg = rowptr[node], end = rowptr[node + 1];
    for (int j = beg; j < end; j += 8) {
        int s0 = colidx[j],     s1 = colidx[j + 1];
        int s2 = colidx[j + 2], s3 = colidx[j + 3];
        int s4 = colidx[j + 4], s5 = colidx[j + 5];
        int s6 = colidx[j + 6], s7 = colidx[j + 7];
        int sw = colidx[j + ce];
        float aw = as_[sw * 4 + ch];
        uint32_t u0 = hb[(size_t)s0 * 64 + lane], u1 = hb[(size_t)s1 * 64 + lane];
        uint32_t u2 = hb[(size_t)s2 * 64 + lane], u3 = hb[(size_t)s3 * 64 + lane];
        uint32_t u4 = hb[(size_t)s4 * 64 + lane], u5 = hb[(size_t)s5 * 64 + lane];
        uint32_t u6 = hb[(size_t)s6 * 64 + lane], u7 = hb[(size_t)s7 * 64 + lane];
        float w = __expf(lrelu(aw + adc));
        float w0 = __shfl(w, 0  + hd), w1 = __shfl(w, 4  + hd);
        float w2 = __shfl(w, 8  + hd), w3 = __shfl(w, 12 + hd);
        float w4 = __shfl(w, 16 + hd), w5 = __shfl(w, 20 + hd);
        float w6 = __shfl(w, 24 + hd), w7 = __shfl(w, 28 + hd);
        accx = fmaf(w0, __uint_as_float(u0 << 16), accx);
        accy = fmaf(w0, __uint_as_float(u0 & 0xFFFF0000u), accy);
        accx = fmaf(w1, __uint_as_float(u1 << 16), accx);
        accy = fmaf(w1, __uint_as_float(u1 & 0xFFFF0000u), accy);
        accx = fmaf(w2, __uint_as_float(u2 << 16), accx);
        accy = fmaf(w2, __uint_as_float(u2 & 0xFFFF0000u), accy);
        accx = fmaf(w3, __uint_as_float(u3 << 16), accx);
        accy = fmaf(w3, __uint_as_float(u3 & 0xFFFF0000u), accy);
        accx = fmaf(w4, __uint_as_float(u4 << 16), accx);
        accy = fmaf(w4, __uint_as_float(u4 & 0xFFFF0000u), accy);
        accx = fmaf(w5, __uint_as_float(u5 << 16), accx);
        accy = fmaf(w5, __uint_as_float(u5 & 0xFFFF0000u), accy);
        accx = fmaf(w6, __uint_as_float(u6 << 16), accx);
        accy = fmaf(w6, __uint_as_float(u6 & 0xFFFF0000u), accy);
        accx = fmaf(w7, __uint_as_float(u7 << 16), accx);
        accy = fmaf(w7, __uint_as_float(u7 & 0xFFFF0000u), accy);
        denom += ((w0 + w1) + (w2 + w3)) + ((w4 + w5) + (w6 + w7));
    }
    float inv = 1.f / (denom + 1e-16f);
    float o0 = fmaf(accx, inv, bias[k]);
    float o1 = fmaf(accy, inv, bias[k + 1]);
    if (do_elu) {
        o0 = o0 > 0.f ? o0 : (__expf(o0) - 1.f);
        o1 = o1 > 0.f ? o1 : (__expf(o1) - 1.f);
    }
    *(float2*)&out[(size_t)node * 128 + k] = make_float2(o0, o1);
}

extern "C" void kernel_launch(void* const* d_in, const int* in_sizes, int n_in,
                              void* d_out, int out_size, void* d_ws, size_t ws_size,
                              hipStream_t stream) {
    const float* x   = (const float*)d_in[0];
    const int*   ei  = (const int*)d_in[1];
    const float* W1  = (const float*)d_in[2];
    const float* a1s = (const float*)d_in[3];
    const float* a1d = (const float*)d_in[4];
    const float* b1  = (const float*)d_in[5];
    const float* W2  = (const float*)d_in[6];
    const float* a2s = (const float*)d_in[7];
    const float* a2d = (const float*)d_in[8];
    const float* b2  = (const float*)d_in[9];
    float* out = (float*)d_out;

    const int N = in_sizes[0] / 128;
    const int E = in_sizes[1] / 2;
    const int* esrc = ei;
    const int* edst = ei + E;

    char* w = (char*)d_ws;
    uint32_t* hbf  = (uint32_t*)w; w += (size_t)(N + 1) * 64 * 4;  // +sentinel row
    float*    as_  = (float*)w;    w += (size_t)(N + 1) * 4 * 4;   // +sentinel
    float*    ad_  = (float*)w;    w += (size_t)(N + 1) * 4 * 4;
    int* deg    = (int*)w;   w += (size_t)N * 4;
    int* rowptr = (int*)w;   w += (size_t)(N + 1) * 4;
    int* rank   = (int*)w;   w += (size_t)E * 4;
    int* colidx = (int*)w;   w += ((size_t)E + 8ull * N) * 4;      // padded CSR
    int* csum   = (int*)w;   w += 256 * 4;
    int* coff   = (int*)w;   w += 256 * 4;
    float* out1 = out;   // layer-1 output in d_out; consumed by layer-2 gemm
                         // before the final aggregate overwrites d_out

    hipMemsetAsync(deg, 0, (size_t)N * 4, stream);

    const int eb = (E + 255) / 256;
    const int ntot = N + 1;
    const int nch = (ntot + 255) / 256;
    const int gb = (N + 127) / 128;
    const int nb = (N + 3) / 4;
    const int pb = (N + 255) / 256;

    // layer-1 GEMM+alpha fused with CSR count/rank (independent work)
    gemm_count<<<gb + eb, 256, 0, stream>>>(x, W1, a1s, a1d, hbf, as_, ad_, N, gb,
                                            edst, E, deg, rank);
    scan1<<<nch, 256, 0, stream>>>(deg, N, ntot, rowptr, csum);
    scan2<<<1, 256, 0, stream>>>(csum, coff, nch);
    scan3<<<nch, 256, 0, stream>>>(rowptr, coff, ntot);
    pad_fill<<<pb, 256, 0, stream>>>(deg, rowptr, colidx, as_, N);
    fill_csr<<<eb, 256, 0, stream>>>(esrc, edst, rank, E, rowptr, colidx);

    aggregate<<<nb, 256, 0, stream>>>(hbf, as_, ad_, rowptr, colidx, b1, out1, N, 1);

    // layer 2
    gemm_alpha<<<gb, 256, 0, stream>>>(out1, W2, a2s, a2d, hbf, as_, ad_, N);
    aggregate<<<nb, 256, 0, stream>>>(hbf, as_, ad_, rowptr, colidx, b2, out, N, 0);
}

// Round 8
// 294.142 us; speedup vs baseline: 1.1379x; 1.1379x over previous
//
#include <hip/hip_runtime.h>
#include <math.h>
#include <stdint.h>

static __device__ __forceinline__ float lrelu(float x) { return x >= 0.f ? x : 0.2f * x; }

// round-to-nearest-even fp32 -> bf16 bits
static __device__ __forceinline__ uint32_t f2bf(float f) {
    uint32_t u = __float_as_uint(f);
    return (u + 0x7FFFu + ((u >> 16) & 1u)) >> 16;
}

// ---------------- CSR build ----------------
// count + rank: the atomic's return value IS the within-node rank.
// Standalone (4 VGPR, no LDS) -> full occupancy; round-6 showed fusing this
// into the GEMM kernel (32KB LDS footprint) regressed 2x.
__global__ __launch_bounds__(256) void count_rank(const int* __restrict__ dst, int E,
                                                  int* __restrict__ deg,
                                                  int* __restrict__ rank) {
    int i = blockIdx.x * 256 + threadIdx.x;
    if (i < E) rank[i] = atomicAdd(&deg[dst[i]], 1);
}

__global__ __launch_bounds__(256) void scan1(const int* __restrict__ deg, int N, int ntot,
                                             int* __restrict__ rowptr, int* __restrict__ csum) {
    __shared__ int s[256];
    int t = threadIdx.x;
    int i = blockIdx.x * 256 + t;
    int v = (i < N) ? ((deg[i] + 15) & ~15) : 0;   // degree padded to mult of 16
    s[t] = v;
    __syncthreads();
    #pragma unroll
    for (int off = 1; off < 256; off <<= 1) {
        int add = (t >= off) ? s[t - off] : 0;
        __syncthreads();
        s[t] += add;
        __syncthreads();
    }
    if (i < ntot) rowptr[i] = s[t] - v;   // exclusive within chunk
    if (t == 255) csum[blockIdx.x] = s[255];
}

__global__ __launch_bounds__(256) void scan2(const int* __restrict__ csum,
                                             int* __restrict__ coff, int nch) {
    __shared__ int s[256];
    int t = threadIdx.x;
    int v = (t < nch) ? csum[t] : 0;
    s[t] = v;
    __syncthreads();
    #pragma unroll
    for (int off = 1; off < 256; off <<= 1) {
        int add = (t >= off) ? s[t - off] : 0;
        __syncthreads();
        s[t] += add;
        __syncthreads();
    }
    coff[t] = s[t] - v;
}

__global__ __launch_bounds__(256) void scan3(int* __restrict__ rowptr,
                                             const int* __restrict__ coff, int ntot) {
    int i = blockIdx.x * 256 + threadIdx.x;
    if (i < ntot) rowptr[i] += coff[blockIdx.x];
}

// Fill pad slots with sentinel node N (weight exactly 0 via as_[N]=-1e30);
// zero the sentinel's bf16 h row (avoid poison values; 0-weight * finite = 0).
__global__ __launch_bounds__(256) void pad_fill(const int* __restrict__ deg,
                                                const int* __restrict__ rowptr,
                                                int* __restrict__ colidx,
                                                float* __restrict__ as_,
                                                uint32_t* __restrict__ hbf, int N) {
    int i = blockIdx.x * 256 + threadIdx.x;
    if (i < 4) as_[N * 4 + i] = -1e30f;
    if (i < 64) hbf[(size_t)N * 64 + i] = 0u;
    if (i < N) {
        int b = rowptr[i] + deg[i];
        int e = rowptr[i + 1];
        for (int p = b; p < e; ++p) colidx[p] = N;
    }
}

__global__ __launch_bounds__(256) void fill_csr(const int* __restrict__ src,
                                                const int* __restrict__ dst,
                                                const int* __restrict__ rank, int E,
                                                const int* __restrict__ rowptr,
                                                int* __restrict__ colidx) {
    int i = blockIdx.x * 256 + threadIdx.x;
    if (i < E) colidx[rowptr[dst[i]] + rank[i]] = src[i];
}

// ---------------- fused GEMM + alpha ----------------
// h[r,128] = x[r,128] @ W[128,128]; writes bf16-packed h, and fused
// as_[r,h] = h.a_src[h], ad_[r,h] = h.a_dst[h] from fp32 registers.
// 128-row tile, BK=32, 256 threads as 16 rowgrp x 16 colgrp, 8x8/thread.
// ws uses a split-halves layout (even col-quads at [k*32+cg], odd at
// [k*32+16+cg]) so the inner-loop reads hit 2 addrs/bank-group (free)
// instead of 4-way conflicts (round-6 profile: 3.2M SQ_LDS_BANK_CONFLICT).
__global__ __launch_bounds__(256) void gemm_alpha(const float* __restrict__ x,
                                                  const float* __restrict__ W,
                                                  const float* __restrict__ a_src,
                                                  const float* __restrict__ a_dst,
                                                  uint32_t* __restrict__ hbf,
                                                  float* __restrict__ as_,
                                                  float* __restrict__ ad_,
                                                  int nrows) {
    __shared__ float xs[128 * 32];
    __shared__ float ws[32 * 128];
    const int t = threadIdx.x;
    const int row0 = blockIdx.x * 128;
    const int rg = t >> 4;           // 0..15
    const int cg = t & 15;           // 0..15
    const int r0 = rg * 8;
    const int c0 = cg * 8;

    float acc[8][8];
    #pragma unroll
    for (int j = 0; j < 8; ++j)
        #pragma unroll
        for (int c = 0; c < 8; ++c) acc[j][c] = 0.f;

    const float4* x4 = (const float4*)x;
    const float4* W4 = (const float4*)W;
    float4* xs4 = (float4*)xs;
    float4* ws4 = (float4*)ws;

    for (int kc = 0; kc < 4; ++kc) {
        #pragma unroll
        for (int i = 0; i < 4; ++i) {       // stage x chunk [128 rows][32 k]
            int idx = t + i * 256;           // 0..1023
            int r = idx >> 3, q = idx & 7;
            float4 v = make_float4(0.f, 0.f, 0.f, 0.f);
            if (row0 + r < nrows) v = x4[(size_t)(row0 + r) * 32 + kc * 8 + q];
            xs4[idx] = v;
        }
        #pragma unroll
        for (int i = 0; i < 4; ++i) {       // stage W chunk, split-halves layout
            int idx = t + i * 256;           // global quad: row k=idx>>5, q=idx&31
            int kk2 = idx >> 5, q = idx & 31;
            int dq = (q & 1) ? (16 + (q >> 1)) : (q >> 1);
            ws4[kk2 * 32 + dq] = W4[kc * 1024 + idx];
        }
        __syncthreads();

        #pragma unroll 2
        for (int kk = 0; kk < 32; kk += 4) {
            float4 xv[8];
            #pragma unroll
            for (int j = 0; j < 8; ++j)
                xv[j] = xs4[(r0 + j) * 8 + (kk >> 2)];
            #pragma unroll
            for (int k2 = 0; k2 < 4; ++k2) {
                int k = kk + k2;
                float4 wv0 = ws4[k * 32 + cg];        // even quad (cols c0..c0+3)
                float4 wv1 = ws4[k * 32 + 16 + cg];   // odd quad  (cols c0+4..c0+7)
                #pragma unroll
                for (int j = 0; j < 8; ++j) {
                    float xk = (k2 == 0) ? xv[j].x : (k2 == 1) ? xv[j].y
                             : (k2 == 2) ? xv[j].z : xv[j].w;
                    acc[j][0] = fmaf(xk, wv0.x, acc[j][0]);
                    acc[j][1] = fmaf(xk, wv0.y, acc[j][1]);
                    acc[j][2] = fmaf(xk, wv0.z, acc[j][2]);
                    acc[j][3] = fmaf(xk, wv0.w, acc[j][3]);
                    acc[j][4] = fmaf(xk, wv1.x, acc[j][4]);
                    acc[j][5] = fmaf(xk, wv1.y, acc[j][5]);
                    acc[j][6] = fmaf(xk, wv1.z, acc[j][6]);
                    acc[j][7] = fmaf(xk, wv1.w, acc[j][7]);
                }
            }
        }
        __syncthreads();
    }

    // epilogue: bf16 h + fused alpha dots (head hd = cg>>2).
    const int hd = cg >> 2;
    float asv[8], adv[8];
    #pragma unroll
    for (int cc = 0; cc < 8; ++cc) {
        asv[cc] = a_src[c0 + cc];
        adv[cc] = a_dst[c0 + cc];
    }
    #pragma unroll
    for (int j = 0; j < 8; ++j) {
        int r = row0 + r0 + j;
        float ps = 0.f, pd = 0.f;
        #pragma unroll
        for (int cc = 0; cc < 8; ++cc) {
            ps = fmaf(acc[j][cc], asv[cc], ps);
            pd = fmaf(acc[j][cc], adv[cc], pd);
        }
        ps += __shfl_xor(ps, 1); ps += __shfl_xor(ps, 2);
        pd += __shfl_xor(pd, 1); pd += __shfl_xor(pd, 2);
        if (r < nrows) {
            uint4 pk;
            pk.x = f2bf(acc[j][0]) | (f2bf(acc[j][1]) << 16);
            pk.y = f2bf(acc[j][2]) | (f2bf(acc[j][3]) << 16);
            pk.z = f2bf(acc[j][4]) | (f2bf(acc[j][5]) << 16);
            pk.w = f2bf(acc[j][6]) | (f2bf(acc[j][7]) << 16);
            *(uint4*)&hbf[(size_t)r * 64 + cg * 4] = pk;
            if ((cg & 3) == 0) {
                as_[r * 4 + hd] = ps;
                ad_[r * 4 + hd] = pd;
            }
        }
    }
}

// ---------------- aggregation: one wave per dst node, bf16 h rows ----------------
// Rows padded to multiple of 16 -> uniform 16-deep gather batches (17
// independent loads in flight per wave). Weight dedup uses ALL 64 lanes:
// lane computes weight of (edge lane>>2, head lane&3); consumers __shfl.
__global__ __launch_bounds__(256) void aggregate(const uint32_t* __restrict__ hb,
                                                 const float* __restrict__ as_,
                                                 const float* __restrict__ ad_,
                                                 const int* __restrict__ rowptr,
                                                 const int* __restrict__ colidx,
                                                 const float* __restrict__ bias,
                                                 float* __restrict__ out, int n, int do_elu) {
    int node = blockIdx.x * 4 + (threadIdx.x >> 6);
    if (node >= n) return;
    int lane = threadIdx.x & 63;
    int hd = lane >> 4;          // head of this lane's 2 output columns
    int k = lane * 2;
    int ce = lane >> 2;          // edge-in-batch this lane weighs (0..15)
    int ch = lane & 3;           // head this lane weighs
    float adn = ad_[node * 4 + hd];
    float adc = ad_[node * 4 + ch];
    float accx = 0.f, accy = 0.f, denom = 0.f;

    {   // self loop
        float wgt = __expf(lrelu(as_[node * 4 + hd] + adn));
        uint32_t u = hb[(size_t)node * 64 + lane];
        accx = fmaf(wgt, __uint_as_float(u << 16), accx);
        accy = fmaf(wgt, __uint_as_float(u & 0xFFFF0000u), accy);
        denom += wgt;
    }
    const int beg = rowptr[node], end = rowptr[node + 1];
    for (int j = beg; j < end; j += 16) {
        int sE[16];
        #pragma unroll
        for (int e = 0; e < 16; ++e) sE[e] = colidx[j + e];
        int sw = colidx[j + ce];                  // edge this lane weighs
        float aw = as_[sw * 4 + ch];
        uint32_t u[16];
        #pragma unroll
        for (int e = 0; e < 16; ++e) u[e] = hb[(size_t)sE[e] * 64 + lane];
        float w = __expf(lrelu(aw + adc));
        #pragma unroll
        for (int e = 0; e < 16; ++e) {
            float we = __shfl(w, e * 4 + hd);
            accx = fmaf(we, __uint_as_float(u[e] << 16), accx);
            accy = fmaf(we, __uint_as_float(u[e] & 0xFFFF0000u), accy);
            denom += we;
        }
    }
    float inv = 1.f / (denom + 1e-16f);
    float o0 = fmaf(accx, inv, bias[k]);
    float o1 = fmaf(accy, inv, bias[k + 1]);
    if (do_elu) {
        o0 = o0 > 0.f ? o0 : (__expf(o0) - 1.f);
        o1 = o1 > 0.f ? o1 : (__expf(o1) - 1.f);
    }
    *(float2*)&out[(size_t)node * 128 + k] = make_float2(o0, o1);
}

extern "C" void kernel_launch(void* const* d_in, const int* in_sizes, int n_in,
                              void* d_out, int out_size, void* d_ws, size_t ws_size,
                              hipStream_t stream) {
    const float* x   = (const float*)d_in[0];
    const int*   ei  = (const int*)d_in[1];
    const float* W1  = (const float*)d_in[2];
    const float* a1s = (const float*)d_in[3];
    const float* a1d = (const float*)d_in[4];
    const float* b1  = (const float*)d_in[5];
    const float* W2  = (const float*)d_in[6];
    const float* a2s = (const float*)d_in[7];
    const float* a2d = (const float*)d_in[8];
    const float* b2  = (const float*)d_in[9];
    float* out = (float*)d_out;

    const int N = in_sizes[0] / 128;
    const int E = in_sizes[1] / 2;
    const int* esrc = ei;
    const int* edst = ei + E;

    char* w = (char*)d_ws;
    uint32_t* hbf  = (uint32_t*)w; w += (size_t)(N + 1) * 64 * 4;  // +sentinel row
    float*    as_  = (float*)w;    w += (size_t)(N + 1) * 4 * 4;   // +sentinel
    float*    ad_  = (float*)w;    w += (size_t)(N + 1) * 4 * 4;
    int* deg    = (int*)w;   w += (size_t)N * 4;
    int* rowptr = (int*)w;   w += (size_t)(N + 1) * 4;
    int* rank   = (int*)w;   w += (size_t)E * 4;
    int* colidx = (int*)w;   w += ((size_t)E + 16ull * N) * 4;     // padded CSR
    int* csum   = (int*)w;   w += 256 * 4;
    int* coff   = (int*)w;   w += 256 * 4;
    float* out1 = out;   // layer-1 output in d_out; consumed by layer-2 gemm
                         // before the final aggregate overwrites d_out

    hipMemsetAsync(deg, 0, (size_t)N * 4, stream);

    const int eb = (E + 255) / 256;
    const int ntot = N + 1;
    const int nch = (ntot + 255) / 256;
    const int gb = (N + 127) / 128;
    const int nb = (N + 3) / 4;
    const int pb = (N + 255) / 256;

    count_rank<<<eb, 256, 0, stream>>>(edst, E, deg, rank);
    scan1<<<nch, 256, 0, stream>>>(deg, N, ntot, rowptr, csum);
    scan2<<<1, 256, 0, stream>>>(csum, coff, nch);
    scan3<<<nch, 256, 0, stream>>>(rowptr, coff, ntot);
    pad_fill<<<pb, 256, 0, stream>>>(deg, rowptr, colidx, as_, hbf, N);
    fill_csr<<<eb, 256, 0, stream>>>(esrc, edst, rank, E, rowptr, colidx);

    // layer 1
    gemm_alpha<<<gb, 256, 0, stream>>>(x, W1, a1s, a1d, hbf, as_, ad_, N);
    aggregate<<<nb, 256, 0, stream>>>(hbf, as_, ad_, rowptr, colidx, b1, out1, N, 1);

    // layer 2
    gemm_alpha<<<gb, 256, 0, stream>>>(out1, W2, a2s, a2d, hbf, as_, ad_, N);
    aggregate<<<nb, 256, 0, stream>>>(hbf, as_, ad_, rowptr, colidx, b2, out, N, 0);
}

// Round 9
// 269.062 us; speedup vs baseline: 1.2439x; 1.0932x over previous
//
#include <hip/hip_runtime.h>
#include <math.h>
#include <stdint.h>

typedef __attribute__((ext_vector_type(8))) short short8;
typedef __attribute__((ext_vector_type(4))) float f32x4;

static __device__ __forceinline__ float lrelu(float x) { return x >= 0.f ? x : 0.2f * x; }

// round-to-nearest-even fp32 -> bf16 bits
static __device__ __forceinline__ uint32_t f2bf(float f) {
    uint32_t u = __float_as_uint(f);
    return (u + 0x7FFFu + ((u >> 16) & 1u)) >> 16;
}

// ---------------- W prep: W[k][col] fp32 -> wtb[col][k] bf16 ----------------
__global__ __launch_bounds__(256) void wprep(const float* __restrict__ W1,
                                             const float* __restrict__ W2,
                                             uint16_t* __restrict__ wtb1,
                                             uint16_t* __restrict__ wtb2) {
    int idx = blockIdx.x * 256 + threadIdx.x;     // 0..32767
    const float* src = (idx < 16384) ? W1 : W2;
    uint16_t* dst = (idx < 16384) ? wtb1 : wtb2;
    int j = idx & 16383;
    int k = j >> 7, col = j & 127;
    dst[col * 128 + k] = (uint16_t)f2bf(src[j]); // src[j] == W[k][col], coalesced read
}

// ---------------- CSR build ----------------
__global__ __launch_bounds__(256) void count_rank(const int* __restrict__ dst, int E,
                                                  int* __restrict__ deg,
                                                  int* __restrict__ rank) {
    int i = blockIdx.x * 256 + threadIdx.x;
    if (i < E) rank[i] = atomicAdd(&deg[dst[i]], 1);
}

__global__ __launch_bounds__(256) void scan1(const int* __restrict__ deg, int N, int ntot,
                                             int* __restrict__ rowptr, int* __restrict__ csum) {
    __shared__ int s[256];
    int t = threadIdx.x;
    int i = blockIdx.x * 256 + t;
    int v = (i < N) ? ((deg[i] + 15) & ~15) : 0;   // degree padded to mult of 16
    s[t] = v;
    __syncthreads();
    #pragma unroll
    for (int off = 1; off < 256; off <<= 1) {
        int add = (t >= off) ? s[t - off] : 0;
        __syncthreads();
        s[t] += add;
        __syncthreads();
    }
    if (i < ntot) rowptr[i] = s[t] - v;
    if (t == 255) csum[blockIdx.x] = s[255];
}

__global__ __launch_bounds__(256) void scan2(const int* __restrict__ csum,
                                             int* __restrict__ coff, int nch) {
    __shared__ int s[256];
    int t = threadIdx.x;
    int v = (t < nch) ? csum[t] : 0;
    s[t] = v;
    __syncthreads();
    #pragma unroll
    for (int off = 1; off < 256; off <<= 1) {
        int add = (t >= off) ? s[t - off] : 0;
        __syncthreads();
        s[t] += add;
        __syncthreads();
    }
    coff[t] = s[t] - v;
}

__global__ __launch_bounds__(256) void scan3(int* __restrict__ rowptr,
                                             const int* __restrict__ coff, int ntot) {
    int i = blockIdx.x * 256 + threadIdx.x;
    if (i < ntot) rowptr[i] += coff[blockIdx.x];
}

// Merged fill: blocks [0,eb) scatter edges (atomic-free via rank);
// blocks [eb, eb+pb) write sentinel pads. Both low-VGPR (homogeneous).
__global__ __launch_bounds__(256) void fill_pad(const int* __restrict__ src,
                                                const int* __restrict__ dst,
                                                const int* __restrict__ rank, int E,
                                                const int* __restrict__ rowptr,
                                                const int* __restrict__ deg,
                                                int* __restrict__ colidx,
                                                float* __restrict__ as_,
                                                uint32_t* __restrict__ hbf, int N, int eb) {
    if ((int)blockIdx.x < eb) {
        int i = blockIdx.x * 256 + threadIdx.x;
        if (i < E) colidx[rowptr[dst[i]] + rank[i]] = src[i];
    } else {
        int i = (blockIdx.x - eb) * 256 + threadIdx.x;
        if (i < 4) as_[N * 4 + i] = -1e30f;        // sentinel weight -> exactly 0
        if (i < 64) hbf[(size_t)N * 64 + i] = 0u;  // sentinel h row = 0
        if (i < N) {
            int b = rowptr[i] + deg[i];
            int e = rowptr[i + 1];
            for (int p = b; p < e; ++p) colidx[p] = N;
        }
    }
}

// ---------------- MFMA GEMM + alpha ----------------
// h[r,128] = x[r,128] @ W[128,128] via mfma_f32_16x16x32_bf16.
// Block: 256 thr (4 waves), 64 rows; wave w owns rows w*16..+15, all 128 cols.
// LDS rows padded to 272B (not 0 mod 128B) -> frag ds_read_b128 is 2-way-bank
// (free). Epilogue bounces D through LDS for coalesced bf16-packed hbf writes
// and per-thread full alpha dots (32 cols = exactly one head, no reduce).
__global__ __launch_bounds__(256) void gemm_mfma(const float* __restrict__ x,
                                                 const uint16_t* __restrict__ wtb,
                                                 const float* __restrict__ a_src,
                                                 const float* __restrict__ a_dst,
                                                 uint32_t* __restrict__ hbf,
                                                 float* __restrict__ as_,
                                                 float* __restrict__ ad_,
                                                 int nrows) {
    __shared__ __align__(16) char lds[52224];      // xs 64*272 | wsT 128*272
    const int t = threadIdx.x;
    const int row0 = blockIdx.x * 64;

    {   // stage x -> bf16 LDS [64 rows][128 k], row stride 272B
        int r = t >> 2;
        int k16b = (t & 3) * 4;
        const float* xrow = x + (size_t)(row0 + r) * 128;
        bool ok = (row0 + r) < nrows;
        #pragma unroll
        for (int i = 0; i < 4; ++i) {
            int k16 = k16b + i;
            float4 va = make_float4(0.f, 0.f, 0.f, 0.f), vb = va;
            if (ok) {
                va = *(const float4*)(xrow + k16 * 8);
                vb = *(const float4*)(xrow + k16 * 8 + 4);
            }
            uint4 pk;
            pk.x = f2bf(va.x) | (f2bf(va.y) << 16);
            pk.y = f2bf(va.z) | (f2bf(va.w) << 16);
            pk.z = f2bf(vb.x) | (f2bf(vb.y) << 16);
            pk.w = f2bf(vb.z) | (f2bf(vb.w) << 16);
            *(uint4*)(lds + r * 272 + k16 * 16) = pk;
        }
    }
    {   // stage wtb (bf16 [col][k]) -> LDS, row stride 272B
        #pragma unroll
        for (int i = 0; i < 8; ++i) {
            int u = t * 8 + i;                     // col = u>>4, k16 = u&15
            int col = u >> 4, k16 = u & 15;
            uint4 v = *(const uint4*)(wtb + col * 128 + k16 * 8);
            *(uint4*)(lds + 17408 + col * 272 + k16 * 16) = v;
        }
    }
    __syncthreads();

    const int w = t >> 6, lane = t & 63;
    const int wrow0 = w * 16;
    const int la = lane & 15, lb = lane >> 4;

    f32x4 acc[8];
    #pragma unroll
    for (int ct = 0; ct < 8; ++ct) acc[ct] = (f32x4){0.f, 0.f, 0.f, 0.f};

    const char* xsb = lds + (wrow0 + la) * 272;
    const char* wsb = lds + 17408;
    #pragma unroll
    for (int kc = 0; kc < 4; ++kc) {
        int k16 = kc * 4 + lb;
        short8 a = *(const short8*)(xsb + k16 * 16);    // A[m=la][k=k16*8..+7]
        #pragma unroll
        for (int ct = 0; ct < 8; ++ct) {
            int col = ct * 16 + la;
            short8 b = *(const short8*)(wsb + col * 272 + k16 * 16); // B[k][n=col]
            acc[ct] = __builtin_amdgcn_mfma_f32_16x16x32_bf16(a, b, acc[ct], 0, 0, 0);
        }
    }
    __syncthreads();

    // D lane layout: col = la, row = lb*4 + r2 (within 16-row tile)
    float* scr = (float*)lds;                      // [64][132] f32
    #pragma unroll
    for (int ct = 0; ct < 8; ++ct)
        #pragma unroll
        for (int r2 = 0; r2 < 4; ++r2)
            scr[(wrow0 + lb * 4 + r2) * 132 + ct * 16 + la] = acc[ct][r2];
    __syncthreads();

    {   // final: thread -> (row, head q); pack hbf + alpha dots
        int row = t >> 2, q = t & 3;
        int grow = row0 + row;
        float v[32];
        #pragma unroll
        for (int m = 0; m < 8; ++m) {
            float4 f = *(const float4*)(scr + row * 132 + q * 32 + m * 4);
            v[m * 4 + 0] = f.x; v[m * 4 + 1] = f.y;
            v[m * 4 + 2] = f.z; v[m * 4 + 3] = f.w;
        }
        if (grow < nrows) {
            uint32_t* orow = hbf + (size_t)grow * 64 + q * 16;
            #pragma unroll
            for (int m2 = 0; m2 < 4; ++m2) {
                uint4 pk;
                pk.x = f2bf(v[m2 * 8 + 0]) | (f2bf(v[m2 * 8 + 1]) << 16);
                pk.y = f2bf(v[m2 * 8 + 2]) | (f2bf(v[m2 * 8 + 3]) << 16);
                pk.z = f2bf(v[m2 * 8 + 4]) | (f2bf(v[m2 * 8 + 5]) << 16);
                pk.w = f2bf(v[m2 * 8 + 6]) | (f2bf(v[m2 * 8 + 7]) << 16);
                *(uint4*)(orow + m2 * 4) = pk;
            }
            float ps = 0.f, pd = 0.f;
            const float* asp = a_src + q * 32;
            const float* adp = a_dst + q * 32;
            #pragma unroll
            for (int j = 0; j < 32; ++j) {
                ps = fmaf(v[j], asp[j], ps);
                pd = fmaf(v[j], adp[j], pd);
            }
            as_[grow * 4 + q] = ps;
            ad_[grow * 4 + q] = pd;
        }
    }
}

// ---------------- aggregation: one wave per dst node, bf16 h rows ----------------
__global__ __launch_bounds__(256) void aggregate(const uint32_t* __restrict__ hb,
                                                 const float* __restrict__ as_,
                                                 const float* __restrict__ ad_,
                                                 const int* __restrict__ rowptr,
                                                 const int* __restrict__ colidx,
                                                 const float* __restrict__ bias,
                                                 float* __restrict__ out, int n, int do_elu) {
    int node = blockIdx.x * 4 + (threadIdx.x >> 6);
    if (node >= n) return;
    int lane = threadIdx.x & 63;
    int hd = lane >> 4;
    int k = lane * 2;
    int ce = lane >> 2;          // edge-in-batch this lane weighs (0..15)
    int ch = lane & 3;           // head this lane weighs
    float adn = ad_[node * 4 + hd];
    float adc = ad_[node * 4 + ch];
    float accx = 0.f, accy = 0.f, denom = 0.f;

    {   // self loop
        float wgt = __expf(lrelu(as_[node * 4 + hd] + adn));
        uint32_t u = hb[(size_t)node * 64 + lane];
        accx = fmaf(wgt, __uint_as_float(u << 16), accx);
        accy = fmaf(wgt, __uint_as_float(u & 0xFFFF0000u), accy);
        denom += wgt;
    }
    const int beg = rowptr[node], end = rowptr[node + 1];
    for (int j = beg; j < end; j += 16) {
        int sE[16];
        #pragma unroll
        for (int e = 0; e < 16; ++e) sE[e] = colidx[j + e];
        int sw = colidx[j + ce];
        float aw = as_[sw * 4 + ch];
        uint32_t u[16];
        #pragma unroll
        for (int e = 0; e < 16; ++e) u[e] = hb[(size_t)sE[e] * 64 + lane];
        float w = __expf(lrelu(aw + adc));
        #pragma unroll
        for (int e = 0; e < 16; ++e) {
            float we = __shfl(w, e * 4 + hd);
            accx = fmaf(we, __uint_as_float(u[e] << 16), accx);
            accy = fmaf(we, __uint_as_float(u[e] & 0xFFFF0000u), accy);
            denom += we;
        }
    }
    float inv = 1.f / (denom + 1e-16f);
    float o0 = fmaf(accx, inv, bias[k]);
    float o1 = fmaf(accy, inv, bias[k + 1]);
    if (do_elu) {
        o0 = o0 > 0.f ? o0 : (__expf(o0) - 1.f);
        o1 = o1 > 0.f ? o1 : (__expf(o1) - 1.f);
    }
    *(float2*)&out[(size_t)node * 128 + k] = make_float2(o0, o1);
}

extern "C" void kernel_launch(void* const* d_in, const int* in_sizes, int n_in,
                              void* d_out, int out_size, void* d_ws, size_t ws_size,
                              hipStream_t stream) {
    const float* x   = (const float*)d_in[0];
    const int*   ei  = (const int*)d_in[1];
    const float* W1  = (const float*)d_in[2];
    const float* a1s = (const float*)d_in[3];
    const float* a1d = (const float*)d_in[4];
    const float* b1  = (const float*)d_in[5];
    const float* W2  = (const float*)d_in[6];
    const float* a2s = (const float*)d_in[7];
    const float* a2d = (const float*)d_in[8];
    const float* b2  = (const float*)d_in[9];
    float* out = (float*)d_out;

    const int N = in_sizes[0] / 128;
    const int E = in_sizes[1] / 2;
    const int* esrc = ei;
    const int* edst = ei + E;

    char* w = (char*)d_ws;
    uint32_t* hbf  = (uint32_t*)w; w += (size_t)(N + 1) * 64 * 4;  // +sentinel row
    float*    as_  = (float*)w;    w += (size_t)(N + 1) * 4 * 4;   // +sentinel
    float*    ad_  = (float*)w;    w += (size_t)(N + 1) * 4 * 4;
    int* deg    = (int*)w;   w += (size_t)N * 4;
    int* rowptr = (int*)w;   w += (size_t)(N + 1) * 4;
    int* rank   = (int*)w;   w += (size_t)E * 4;
    int* colidx = (int*)w;   w += ((size_t)E + 16ull * N) * 4;     // padded CSR
    int* csum   = (int*)w;   w += 256 * 4;
    int* coff   = (int*)w;   w += 256 * 4;
    uint16_t* wtb1 = (uint16_t*)w; w += 16384 * 2;                 // bf16 W1^T [col][k]
    uint16_t* wtb2 = (uint16_t*)w; w += 16384 * 2;                 // bf16 W2^T
    float* out1 = out;   // layer-1 output in d_out; consumed by layer-2 gemm
                         // before the final aggregate overwrites d_out

    hipMemsetAsync(deg, 0, (size_t)N * 4, stream);

    const int eb = (E + 255) / 256;
    const int ntot = N + 1;
    const int nch = (ntot + 255) / 256;
    const int gb = (N + 63) / 64;
    const int nb = (N + 3) / 4;
    const int pb = (N + 255) / 256;

    wprep<<<128, 256, 0, stream>>>(W1, W2, wtb1, wtb2);
    count_rank<<<eb, 256, 0, stream>>>(edst, E, deg, rank);
    scan1<<<nch, 256, 0, stream>>>(deg, N, ntot, rowptr, csum);
    scan2<<<1, 256, 0, stream>>>(csum, coff, nch);
    scan3<<<nch, 256, 0, stream>>>(rowptr, coff, ntot);
    fill_pad<<<eb + pb, 256, 0, stream>>>(esrc, edst, rank, E, rowptr, deg,
                                          colidx, as_, hbf, N, eb);

    // layer 1
    gemm_mfma<<<gb, 256, 0, stream>>>(x, wtb1, a1s, a1d, hbf, as_, ad_, N);
    aggregate<<<nb, 256, 0, stream>>>(hbf, as_, ad_, rowptr, colidx, b1, out1, N, 1);

    // layer 2
    gemm_mfma<<<gb, 256, 0, stream>>>(out1, wtb2, a2s, a2d, hbf, as_, ad_, N);
    aggregate<<<nb, 256, 0, stream>>>(hbf, as_, ad_, rowptr, colidx, b2, out, N, 0);
}

// Round 10
// 261.719 us; speedup vs baseline: 1.2788x; 1.0281x over previous
//
#include <hip/hip_runtime.h>
#include <math.h>
#include <stdint.h>

typedef __attribute__((ext_vector_type(8))) short short8;
typedef __attribute__((ext_vector_type(4))) float f32x4;

static __device__ __forceinline__ float lrelu(float x) { return x >= 0.f ? x : 0.2f * x; }

// round-to-nearest-even fp32 -> bf16 bits
static __device__ __forceinline__ uint32_t f2bf(float f) {
    uint32_t u = __float_as_uint(f);
    return (u + 0x7FFFu + ((u >> 16) & 1u)) >> 16;
}

// ---------------- count (XCD-partitioned) + wprep ----------------
// deg8[part][node], part=blockIdx&7: blocks round-robin to XCDs, so each
// counter line stays in ONE XCD's L2 (kills cross-XCD RMW line ping-pong,
// the diagnosed count_rank bottleneck). rank[i] = within-partition rank.
// Blocks [eb, eb+128) additionally do W transpose->bf16 (tiny, homogeneous).
__global__ __launch_bounds__(256) void count_wprep(const int* __restrict__ dst, int E, int N,
                                                   int* __restrict__ deg8,
                                                   int* __restrict__ rank, int eb,
                                                   const float* __restrict__ W1,
                                                   const float* __restrict__ W2,
                                                   uint16_t* __restrict__ wtb1,
                                                   uint16_t* __restrict__ wtb2) {
    if ((int)blockIdx.x < eb) {
        int i = blockIdx.x * 256 + threadIdx.x;
        int p = blockIdx.x & 7;
        if (i < E) rank[i] = atomicAdd(&deg8[p * N + dst[i]], 1);
    } else {
        int idx = (blockIdx.x - eb) * 256 + threadIdx.x;   // 0..32767
        const float* src = (idx < 16384) ? W1 : W2;
        uint16_t* dw = (idx < 16384) ? wtb1 : wtb2;
        int j = idx & 16383;
        dw[(j & 127) * 128 + (j >> 7)] = (uint16_t)f2bf(src[j]);  // [col][k]
    }
}

// ---------------- scan1: combine partitions + chunk-scan padded degrees ----
__global__ __launch_bounds__(256) void scan1(const int* __restrict__ deg8, int N, int ntot,
                                             int* __restrict__ deg,
                                             int* __restrict__ base8,
                                             int* __restrict__ rowptr,
                                             int* __restrict__ csum) {
    __shared__ int s[256];
    int t = threadIdx.x;
    int i = blockIdx.x * 256 + t;
    int v = 0;
    if (i < N) {
        int total = 0;
        #pragma unroll
        for (int p = 0; p < 8; ++p) {
            int c = deg8[p * N + i];
            base8[p * N + i] = total;      // prefix over partitions
            total += c;
        }
        deg[i] = total;
        v = (total + 15) & ~15;            // degree padded to mult of 16
    }
    s[t] = v;
    __syncthreads();
    #pragma unroll
    for (int off = 1; off < 256; off <<= 1) {
        int add = (t >= off) ? s[t - off] : 0;
        __syncthreads();
        s[t] += add;
        __syncthreads();
    }
    if (i < ntot) rowptr[i] = s[t] - v;    // exclusive within chunk
    if (t == 255) csum[blockIdx.x] = s[255];
}

__global__ __launch_bounds__(256) void scan2(const int* __restrict__ csum,
                                             int* __restrict__ coff, int nch) {
    __shared__ int s[256];
    int t = threadIdx.x;
    int v = (t < nch) ? csum[t] : 0;
    s[t] = v;
    __syncthreads();
    #pragma unroll
    for (int off = 1; off < 256; off <<= 1) {
        int add = (t >= off) ? s[t - off] : 0;
        __syncthreads();
        s[t] += add;
        __syncthreads();
    }
    coff[t] = s[t] - v;
}

__global__ __launch_bounds__(256) void scan3(int* __restrict__ rowptr,
                                             const int* __restrict__ coff, int ntot) {
    int i = blockIdx.x * 256 + threadIdx.x;
    if (i < ntot) rowptr[i] += coff[blockIdx.x];
}

// Merged fill: blocks [0,eb) scatter edges (atomic-free; same grid geometry
// as count_wprep so part=blockIdx&7 matches); blocks [eb,..) write sentinel
// + pads. colidx is uint16 (N+1 = 50001 < 65536).
__global__ __launch_bounds__(256) void fill_pad(const int* __restrict__ src,
                                                const int* __restrict__ dst,
                                                const int* __restrict__ rank, int E, int N,
                                                const int* __restrict__ rowptr,
                                                const int* __restrict__ deg,
                                                const int* __restrict__ base8,
                                                uint16_t* __restrict__ colidx,
                                                float* __restrict__ as_,
                                                uint32_t* __restrict__ hbf, int eb) {
    if ((int)blockIdx.x < eb) {
        int i = blockIdx.x * 256 + threadIdx.x;
        int p = blockIdx.x & 7;
        if (i < E) {
            int d = dst[i];
            colidx[rowptr[d] + base8[p * N + d] + rank[i]] = (uint16_t)src[i];
        }
    } else {
        int i = (blockIdx.x - eb) * 256 + threadIdx.x;
        if (i < 4) as_[N * 4 + i] = -1e30f;        // sentinel weight -> exactly 0
        if (i < 64) hbf[(size_t)N * 64 + i] = 0u;  // sentinel h row = 0
        if (i < N) {
            int b = rowptr[i] + deg[i];
            int e = rowptr[i + 1];
            for (int pp = b; pp < e; ++pp) colidx[pp] = (uint16_t)N;
        }
    }
}

// ---------------- MFMA GEMM + alpha ----------------
// h[r,128] = x[r,128] @ W[128,128] via mfma_f32_16x16x32_bf16 (round-9 design).
__global__ __launch_bounds__(256) void gemm_mfma(const float* __restrict__ x,
                                                 const uint16_t* __restrict__ wtb,
                                                 const float* __restrict__ a_src,
                                                 const float* __restrict__ a_dst,
                                                 uint32_t* __restrict__ hbf,
                                                 float* __restrict__ as_,
                                                 float* __restrict__ ad_,
                                                 int nrows) {
    __shared__ __align__(16) char lds[52224];      // xs 64*272 | wsT 128*272
    const int t = threadIdx.x;
    const int row0 = blockIdx.x * 64;

    {   // stage x -> bf16 LDS [64 rows][128 k], row stride 272B
        int r = t >> 2;
        int k16b = (t & 3) * 4;
        const float* xrow = x + (size_t)(row0 + r) * 128;
        bool ok = (row0 + r) < nrows;
        #pragma unroll
        for (int i = 0; i < 4; ++i) {
            int k16 = k16b + i;
            float4 va = make_float4(0.f, 0.f, 0.f, 0.f), vb = va;
            if (ok) {
                va = *(const float4*)(xrow + k16 * 8);
                vb = *(const float4*)(xrow + k16 * 8 + 4);
            }
            uint4 pk;
            pk.x = f2bf(va.x) | (f2bf(va.y) << 16);
            pk.y = f2bf(va.z) | (f2bf(va.w) << 16);
            pk.z = f2bf(vb.x) | (f2bf(vb.y) << 16);
            pk.w = f2bf(vb.z) | (f2bf(vb.w) << 16);
            *(uint4*)(lds + r * 272 + k16 * 16) = pk;
        }
    }
    {   // stage wtb (bf16 [col][k]) -> LDS, row stride 272B
        #pragma unroll
        for (int i = 0; i < 8; ++i) {
            int u = t * 8 + i;
            int col = u >> 4, k16 = u & 15;
            uint4 v = *(const uint4*)(wtb + col * 128 + k16 * 8);
            *(uint4*)(lds + 17408 + col * 272 + k16 * 16) = v;
        }
    }
    __syncthreads();

    const int w = t >> 6, lane = t & 63;
    const int wrow0 = w * 16;
    const int la = lane & 15, lb = lane >> 4;

    f32x4 acc[8];
    #pragma unroll
    for (int ct = 0; ct < 8; ++ct) acc[ct] = (f32x4){0.f, 0.f, 0.f, 0.f};

    const char* xsb = lds + (wrow0 + la) * 272;
    const char* wsb = lds + 17408;
    #pragma unroll
    for (int kc = 0; kc < 4; ++kc) {
        int k16 = kc * 4 + lb;
        short8 a = *(const short8*)(xsb + k16 * 16);
        #pragma unroll
        for (int ct = 0; ct < 8; ++ct) {
            int col = ct * 16 + la;
            short8 b = *(const short8*)(wsb + col * 272 + k16 * 16);
            acc[ct] = __builtin_amdgcn_mfma_f32_16x16x32_bf16(a, b, acc[ct], 0, 0, 0);
        }
    }
    __syncthreads();

    // D lane layout: col = la, row = lb*4 + r2 (within 16-row tile)
    float* scr = (float*)lds;                      // [64][132] f32
    #pragma unroll
    for (int ct = 0; ct < 8; ++ct)
        #pragma unroll
        for (int r2 = 0; r2 < 4; ++r2)
            scr[(wrow0 + lb * 4 + r2) * 132 + ct * 16 + la] = acc[ct][r2];
    __syncthreads();

    {   // final: thread -> (row, head q); pack hbf + alpha dots
        int row = t >> 2, q = t & 3;
        int grow = row0 + row;
        float v[32];
        #pragma unroll
        for (int m = 0; m < 8; ++m) {
            float4 f = *(const float4*)(scr + row * 132 + q * 32 + m * 4);
            v[m * 4 + 0] = f.x; v[m * 4 + 1] = f.y;
            v[m * 4 + 2] = f.z; v[m * 4 + 3] = f.w;
        }
        if (grow < nrows) {
            uint32_t* orow = hbf + (size_t)grow * 64 + q * 16;
            #pragma unroll
            for (int m2 = 0; m2 < 4; ++m2) {
                uint4 pk;
                pk.x = f2bf(v[m2 * 8 + 0]) | (f2bf(v[m2 * 8 + 1]) << 16);
                pk.y = f2bf(v[m2 * 8 + 2]) | (f2bf(v[m2 * 8 + 3]) << 16);
                pk.z = f2bf(v[m2 * 8 + 4]) | (f2bf(v[m2 * 8 + 5]) << 16);
                pk.w = f2bf(v[m2 * 8 + 6]) | (f2bf(v[m2 * 8 + 7]) << 16);
                *(uint4*)(orow + m2 * 4) = pk;
            }
            float ps = 0.f, pd = 0.f;
            const float* asp = a_src + q * 32;
            const float* adp = a_dst + q * 32;
            #pragma unroll
            for (int j = 0; j < 32; ++j) {
                ps = fmaf(v[j], asp[j], ps);
                pd = fmaf(v[j], adp[j], pd);
            }
            as_[grow * 4 + q] = ps;
            ad_[grow * 4 + q] = pd;
        }
    }
}

// ---------------- aggregation: one wave per dst node, bf16 h rows ----------------
// colidx is u16; each 16-edge batch read as two wave-uniform uint4 loads.
__global__ __launch_bounds__(256) void aggregate(const uint32_t* __restrict__ hb,
                                                 const float* __restrict__ as_,
                                                 const float* __restrict__ ad_,
                                                 const int* __restrict__ rowptr,
                                                 const uint16_t* __restrict__ colidx,
                                                 const float* __restrict__ bias,
                                                 float* __restrict__ out, int n, int do_elu) {
    int node = blockIdx.x * 4 + (threadIdx.x >> 6);
    if (node >= n) return;
    int lane = threadIdx.x & 63;
    int hd = lane >> 4;
    int k = lane * 2;
    int ce = lane >> 2;          // edge-in-batch this lane weighs (0..15)
    int ch = lane & 3;           // head this lane weighs
    float adn = ad_[node * 4 + hd];
    float adc = ad_[node * 4 + ch];
    float accx = 0.f, accy = 0.f, denom = 0.f;

    {   // self loop
        float wgt = __expf(lrelu(as_[node * 4 + hd] + adn));
        uint32_t u = hb[(size_t)node * 64 + lane];
        accx = fmaf(wgt, __uint_as_float(u << 16), accx);
        accy = fmaf(wgt, __uint_as_float(u & 0xFFFF0000u), accy);
        denom += wgt;
    }
    const int beg = rowptr[node], end = rowptr[node + 1];
    for (int j = beg; j < end; j += 16) {
        uint4 cA = *(const uint4*)(colidx + j);       // edges 0..7 (u16 x8)
        uint4 cB = *(const uint4*)(colidx + j + 8);   // edges 8..15
        int sE[16];
        sE[0]  = cA.x & 0xFFFF; sE[1]  = cA.x >> 16;
        sE[2]  = cA.y & 0xFFFF; sE[3]  = cA.y >> 16;
        sE[4]  = cA.z & 0xFFFF; sE[5]  = cA.z >> 16;
        sE[6]  = cA.w & 0xFFFF; sE[7]  = cA.w >> 16;
        sE[8]  = cB.x & 0xFFFF; sE[9]  = cB.x >> 16;
        sE[10] = cB.y & 0xFFFF; sE[11] = cB.y >> 16;
        sE[12] = cB.z & 0xFFFF; sE[13] = cB.z >> 16;
        sE[14] = cB.w & 0xFFFF; sE[15] = cB.w >> 16;
        int sw = colidx[j + ce];                      // per-lane scalar (no reg-indexing)
        float aw = as_[sw * 4 + ch];
        uint32_t u[16];
        #pragma unroll
        for (int e = 0; e < 16; ++e) u[e] = hb[(size_t)sE[e] * 64 + lane];
        float w = __expf(lrelu(aw + adc));
        #pragma unroll
        for (int e = 0; e < 16; ++e) {
            float we = __shfl(w, e * 4 + hd);
            accx = fmaf(we, __uint_as_float(u[e] << 16), accx);
            accy = fmaf(we, __uint_as_float(u[e] & 0xFFFF0000u), accy);
            denom += we;
        }
    }
    float inv = 1.f / (denom + 1e-16f);
    float o0 = fmaf(accx, inv, bias[k]);
    float o1 = fmaf(accy, inv, bias[k + 1]);
    if (do_elu) {
        o0 = o0 > 0.f ? o0 : (__expf(o0) - 1.f);
        o1 = o1 > 0.f ? o1 : (__expf(o1) - 1.f);
    }
    *(float2*)&out[(size_t)node * 128 + k] = make_float2(o0, o1);
}

extern "C" void kernel_launch(void* const* d_in, const int* in_sizes, int n_in,
                              void* d_out, int out_size, void* d_ws, size_t ws_size,
                              hipStream_t stream) {
    const float* x   = (const float*)d_in[0];
    const int*   ei  = (const int*)d_in[1];
    const float* W1  = (const float*)d_in[2];
    const float* a1s = (const float*)d_in[3];
    const float* a1d = (const float*)d_in[4];
    const float* b1  = (const float*)d_in[5];
    const float* W2  = (const float*)d_in[6];
    const float* a2s = (const float*)d_in[7];
    const float* a2d = (const float*)d_in[8];
    const float* b2  = (const float*)d_in[9];
    float* out = (float*)d_out;

    const int N = in_sizes[0] / 128;   // 50000; N+1 fits uint16 (colidx)
    const int E = in_sizes[1] / 2;
    const int* esrc = ei;
    const int* edst = ei + E;

    char* w = (char*)d_ws;
    uint32_t* hbf  = (uint32_t*)w; w += (size_t)(N + 1) * 64 * 4;  // +sentinel row
    float*    as_  = (float*)w;    w += (size_t)(N + 1) * 4 * 4;   // +sentinel
    float*    ad_  = (float*)w;    w += (size_t)(N + 1) * 4 * 4;
    int* deg    = (int*)w;   w += (size_t)N * 4;
    int* rowptr = (int*)w;   w += (size_t)(N + 1) * 4;
    int* rank   = (int*)w;   w += (size_t)E * 4;
    int* deg8   = (int*)w;   w += (size_t)8 * N * 4;               // per-XCD counters
    int* base8  = (int*)w;   w += (size_t)8 * N * 4;               // partition prefixes
    int* csum   = (int*)w;   w += 256 * 4;
    int* coff   = (int*)w;   w += 256 * 4;
    uint16_t* wtb1 = (uint16_t*)w; w += 16384 * 2;                 // bf16 W1^T [col][k]
    uint16_t* wtb2 = (uint16_t*)w; w += 16384 * 2;
    w = (char*)(((uintptr_t)w + 31) & ~(uintptr_t)31);             // 32B align
    uint16_t* colidx = (uint16_t*)w; w += ((size_t)E + 16ull * N) * 2;  // padded CSR, u16
    float* out1 = out;   // layer-1 output in d_out; consumed by layer-2 gemm
                         // before the final aggregate overwrites d_out

    hipMemsetAsync(deg8, 0, (size_t)8 * N * 4, stream);

    const int eb = (E + 255) / 256;
    const int ntot = N + 1;
    const int nch = (ntot + 255) / 256;
    const int gb = (N + 63) / 64;
    const int nb = (N + 3) / 4;
    const int pb = (N + 255) / 256;

    count_wprep<<<eb + 128, 256, 0, stream>>>(edst, E, N, deg8, rank, eb,
                                              W1, W2, wtb1, wtb2);
    scan1<<<nch, 256, 0, stream>>>(deg8, N, ntot, deg, base8, rowptr, csum);
    scan2<<<1, 256, 0, stream>>>(csum, coff, nch);
    scan3<<<nch, 256, 0, stream>>>(rowptr, coff, ntot);
    fill_pad<<<eb + pb, 256, 0, stream>>>(esrc, edst, rank, E, N, rowptr, deg,
                                          base8, colidx, as_, hbf, eb);

    // layer 1
    gemm_mfma<<<gb, 256, 0, stream>>>(x, wtb1, a1s, a1d, hbf, as_, ad_, N);
    aggregate<<<nb, 256, 0, stream>>>(hbf, as_, ad_, rowptr, colidx, b1, out1, N, 1);

    // layer 2
    gemm_mfma<<<gb, 256, 0, stream>>>(out1, wtb2, a2s, a2d, hbf, as_, ad_, N);
    aggregate<<<nb, 256, 0, stream>>>(hbf, as_, ad_, rowptr, colidx, b2, out, N, 0);
}